// Round 6
// baseline (898.474 us; speedup 1.0000x reference)
//
#include <hip/hip_runtime.h>

// Problem constants
#define D    128      // d+1
#define DM   127      // d
#define NP1  1024     // N+1
#define B    8
#define H    8
#define NL   4
#define DD   16384    // 128*128
#define INVN (1.0f / 1023.0f)

// Workspace (float offsets) — exactly 6 MB (round-3 proven size)
// Gp [B][4][128][128]  : 524288   (Gram partials, 4 token-chunks of 256)
// S  [NL][B][128][128] : 524288   (head-reduced raw S sums, atomically built)
// GA/GB [B][128][128]  : 131072 each (G ping-pong)
// CA/CB [B][128][128]  : 131072 each (C ping-pong)

// ---------------------------------------------------------------------------
// init: C=I, S[0..3]=0, Gram partials Gp from Z0. 256 blocks.
// block gid -> (c:4 token-chunks of 256, q:8 col-slices of 16, b:8)
// ---------------------------------------------------------------------------
__global__ __launch_bounds__(256) void init_kernel(
    const float* __restrict__ Z0, float* __restrict__ Gp,
    float* __restrict__ Cid, float* __restrict__ Sz)
{
    const int gid = blockIdx.x;
    const int t = threadIdx.x;
    __shared__ float lds[64 * 128];   // 32 KB

    // C = I (131072 elems, 2 per thread)
    #pragma unroll
    for (int e = 0; e < 2; ++e) {
        const int idx = gid * 256 + t + 65536 * e;
        const int r = (idx >> 7) & 127, c = idx & 127;
        Cid[idx] = (r == c) ? 1.f : 0.f;
    }
    // S[0..3] = 0 (131072 float4, 2 per thread)
    #pragma unroll
    for (int e = 0; e < 2; ++e)
        ((float4*)Sz)[gid * 256 + t + 65536 * e] = make_float4(0.f, 0.f, 0.f, 0.f);

    // Gram partials
    const int c = gid & 3;
    const int q = (gid >> 2) & 7;
    const int b = gid >> 5;
    const int i0 = 4 * (t >> 3);          // rows i0..i0+4
    const int j0 = q * 16 + 2 * (t & 7);  // 2 cols

    float acc[4][2] = {};
    #pragma unroll
    for (int pass = 0; pass < 4; ++pass) {
        __syncthreads();
        const float4* src = (const float4*)(Z0 + ((size_t)b * NP1 + c * 256 + pass * 64) * D);
        #pragma unroll
        for (int i = 0; i < 8; ++i) {
            float4 v = src[t + 256 * i];
            // token 1023 (key-masked) = chunk 3, pass 3, last 8 rows
            if (c == 3 && pass == 3 && i == 7 && t >= 224) v = make_float4(0.f, 0.f, 0.f, 0.f);
            ((float4*)lds)[t + 256 * i] = v;
        }
        __syncthreads();
        #pragma unroll 4
        for (int k = 0; k < 64; ++k) {
            const float4 a = *(const float4*)&lds[k * 128 + i0];
            const float c0 = lds[k * 128 + j0];
            const float c1 = lds[k * 128 + j0 + 1];
            acc[0][0] += a.x * c0; acc[0][1] += a.x * c1;
            acc[1][0] += a.y * c0; acc[1][1] += a.y * c1;
            acc[2][0] += a.z * c0; acc[2][1] += a.z * c1;
            acc[3][0] += a.w * c0; acc[3][1] += a.w * c1;
        }
    }
    float* Gb = Gp + (size_t)(b * 4 + c) * DD;
    #pragma unroll
    for (int r = 0; r < 4; ++r)
        *(float2*)&Gb[(i0 + r) * D + j0] = make_float2(acc[r][0], acc[r][1]);
}

// ---------------------------------------------------------------------------
// sp: S_l[b] += Q̂_h G P̂_hᵀ (atomic over heads). grid (4 slices, 8 h, 8 b).
// Q̂/P̂ staged padded directly from raw params. gp_mode: G = sum of 4 Gp chunks.
// ---------------------------------------------------------------------------
__global__ __launch_bounds__(256) void sp_kernel(
    const float* __restrict__ apl, const float* __restrict__ Gsrc,
    float* __restrict__ Sl, int gp_mode)
{
    const int s = blockIdx.x;   // 0..3
    const int h = blockIdx.y;
    const int b = blockIdx.z;
    const int t = threadIdx.x;
    const int ty = t >> 3;      // 0..31 local row
    const int tx = t & 7;
    const int i0 = s * 32;

    __shared__ float Qs[32 * 132];
    __shared__ float Ck[16 * 132];
    __shared__ float Ts[32 * 132];

    // stage padded Q̂ rows [i0, i0+32)   (Q = params[:,1])
    const float* Qsrc = apl + (h * 2 + 1) * DM * DM;
    #pragma unroll
    for (int e = 0; e < 16; ++e) {
        const int idx = t + 256 * e;          // 0..4095
        const int rr = idx >> 7, c = idx & 127;
        const int r = i0 + rr;
        Qs[rr * 132 + c] = (r < DM && c < DM) ? Qsrc[r * DM + c] : 0.f;
    }

    // ---- phase 1: T = Q̂_slice @ G ----
    float4 acc[4] = {make_float4(0,0,0,0), make_float4(0,0,0,0),
                     make_float4(0,0,0,0), make_float4(0,0,0,0)};
    for (int kc = 0; kc < 8; ++kc) {
        __syncthreads();   // covers Qs on kc==0, Ck reuse after
        #pragma unroll
        for (int u = 0; u < 2; ++u) {
            const int idx4 = t + 256 * u;     // 0..511 (float4 within 16x128)
            float4 v;
            if (gp_mode) {
                v = make_float4(0.f, 0.f, 0.f, 0.f);
                #pragma unroll
                for (int cc = 0; cc < 4; ++cc) {
                    const float4 g = ((const float4*)Gsrc)[(size_t)(b * 4 + cc) * 4096 + kc * 512 + idx4];
                    v.x += g.x; v.y += g.y; v.z += g.z; v.w += g.w;
                }
            } else {
                v = ((const float4*)Gsrc)[(size_t)b * 4096 + kc * 512 + idx4];
            }
            const int pos = idx4 << 2;
            *(float4*)&Ck[(pos >> 7) * 132 + (pos & 127)] = v;
        }
        __syncthreads();
        #pragma unroll
        for (int kk = 0; kk < 16; ++kk) {
            const float tv = Qs[ty * 132 + kc * 16 + kk];
            #pragma unroll
            for (int j4 = 0; j4 < 4; ++j4) {
                const float4 g = *(const float4*)&Ck[kk * 132 + 4 * tx + 32 * j4];
                acc[j4].x += tv * g.x; acc[j4].y += tv * g.y;
                acc[j4].z += tv * g.z; acc[j4].w += tv * g.w;
            }
        }
    }
    #pragma unroll
    for (int j4 = 0; j4 < 4; ++j4)
        *(float4*)&Ts[ty * 132 + 4 * tx + 32 * j4] = acc[j4];

    // ---- phase 2: out = T @ P̂ᵀ, P̂ rows staged padded (P = params[:,0]) ----
    const float* Psrc = apl + (h * 2 + 0) * DM * DM;
    for (int jc = 0; jc < 8; ++jc) {
        __syncthreads();   // covers Ts writes on jc==0, Pc(Ck) reuse after
        #pragma unroll
        for (int e = 0; e < 8; ++e) {
            const int idx = t + 256 * e;      // 0..2047
            const int jj = idx >> 7, k = idx & 127;
            const int j = jc * 16 + jj;
            float v;
            if (j < DM && k < DM)        v = Psrc[j * DM + k];
            else if (j == DM && k == DM) v = 1.f;
            else                         v = 0.f;
            Ck[jj * 132 + k] = v;
        }
        __syncthreads();
        float x0 = 0.f, x1 = 0.f;
        #pragma unroll 8
        for (int k4 = 0; k4 < 32; ++k4) {
            const float4 tv = *(const float4*)&Ts[ty * 132 + 4 * k4];
            const float4 p0 = *(const float4*)&Ck[tx * 132 + 4 * k4];
            const float4 p1 = *(const float4*)&Ck[(tx + 8) * 132 + 4 * k4];
            x0 += tv.x * p0.x + tv.y * p0.y + tv.z * p0.z + tv.w * p0.w;
            x1 += tv.x * p1.x + tv.y * p1.y + tv.z * p1.z + tv.w * p1.w;
        }
        atomicAdd(&Sl[(size_t)b * DD + (i0 + ty) * D + jc * 16 + tx], x0);
        atomicAdd(&Sl[(size_t)b * DD + (i0 + ty) * D + jc * 16 + tx + 8], x1);
    }
}

// ---------------------------------------------------------------------------
// upd: A = I + S/N;  G-blocks (s<4): Gout = Aᵀ G A;  C-blocks (s>=4): Cout = Cin A.
// grid (8, 8). gp_mode: G streamed as 4-chunk Gp reduce. do_g=0 skips G-blocks.
// ---------------------------------------------------------------------------
__global__ __launch_bounds__(256) void upd_kernel(
    const float* __restrict__ Sl, const float* __restrict__ Gsrc,
    const float* __restrict__ Cin, float* __restrict__ Gout,
    float* __restrict__ Cout, int gp_mode, int do_g)
{
    const int s = blockIdx.x;   // 0..7
    const int b = blockIdx.y;
    const int t = threadIdx.x;
    const int ty = t >> 3, tx = t & 7;
    const bool gtype = (s < 4);
    const int i0 = (gtype ? s : s - 4) * 32;

    if (gtype && !do_g) return;

    __shared__ float Acs[128 * 36];
    __shared__ float Ck[16 * 132];
    __shared__ float Xs[32 * 132];

    if (gtype) {
        // Acs[k][ii] = A[k][i0+ii]
        #pragma unroll
        for (int e = 0; e < 16; ++e) {
            const int idx = t + 256 * e;       // 0..4095
            const int k = idx >> 5, ii = idx & 31;
            float v = INVN * Sl[(size_t)b * DD + k * D + i0 + ii];
            if (k == i0 + ii) v += 1.f;
            Acs[k * 36 + ii] = v;
        }
        __syncthreads();
        // phase A: X = A_colsliceᵀ @ G
        float4 acc[4] = {make_float4(0,0,0,0), make_float4(0,0,0,0),
                         make_float4(0,0,0,0), make_float4(0,0,0,0)};
        for (int kc = 0; kc < 8; ++kc) {
            if (kc) __syncthreads();
            #pragma unroll
            for (int u = 0; u < 2; ++u) {
                const int idx4 = t + 256 * u;
                float4 v;
                if (gp_mode) {
                    v = make_float4(0.f, 0.f, 0.f, 0.f);
                    #pragma unroll
                    for (int cc = 0; cc < 4; ++cc) {
                        const float4 g = ((const float4*)Gsrc)[(size_t)(b * 4 + cc) * 4096 + kc * 512 + idx4];
                        v.x += g.x; v.y += g.y; v.z += g.z; v.w += g.w;
                    }
                } else {
                    v = ((const float4*)Gsrc)[(size_t)b * 4096 + kc * 512 + idx4];
                }
                const int pos = idx4 << 2;
                *(float4*)&Ck[(pos >> 7) * 132 + (pos & 127)] = v;
            }
            __syncthreads();
            #pragma unroll
            for (int kk = 0; kk < 16; ++kk) {
                const float a = Acs[(kc * 16 + kk) * 36 + ty];
                #pragma unroll
                for (int j4 = 0; j4 < 4; ++j4) {
                    const float4 g = *(const float4*)&Ck[kk * 132 + 4 * tx + 32 * j4];
                    acc[j4].x += a * g.x; acc[j4].y += a * g.y;
                    acc[j4].z += a * g.z; acc[j4].w += a * g.w;
                }
            }
        }
        #pragma unroll
        for (int j4 = 0; j4 < 4; ++j4)
            *(float4*)&Xs[ty * 132 + 4 * tx + 32 * j4] = acc[j4];
    } else {
        // X = Cin rows [i0, i0+32)
        #pragma unroll
        for (int e = 0; e < 4; ++e) {
            const int idx4 = t + 256 * e;       // 0..1023 float4 of 32x128
            const int pos = idx4 << 2;
            *(float4*)&Xs[(pos >> 7) * 132 + (pos & 127)] =
                ((const float4*)Cin)[(size_t)b * 4096 + i0 * 32 + idx4];
        }
    }

    // ---- phase B: Out rows = X @ A ----
    float4 acc2[4] = {make_float4(0,0,0,0), make_float4(0,0,0,0),
                      make_float4(0,0,0,0), make_float4(0,0,0,0)};
    for (int kc = 0; kc < 8; ++kc) {
        __syncthreads();   // covers Xs writes on kc==0 and Ck reuse
        #pragma unroll
        for (int u = 0; u < 2; ++u) {
            const int idx4 = t + 256 * u;
            const int pos = idx4 << 2;
            const int kk = pos >> 7, col = pos & 127;
            const float4 sv = ((const float4*)Sl)[(size_t)b * 4096 + kc * 512 + idx4];
            float4 v = make_float4(sv.x * INVN, sv.y * INVN, sv.z * INVN, sv.w * INVN);
            const int k = kc * 16 + kk;
            if (k >= col && k < col + 4) (&v.x)[k - col] += 1.f;   // + I
            *(float4*)&Ck[kk * 132 + col] = v;
        }
        __syncthreads();
        #pragma unroll
        for (int kk = 0; kk < 16; ++kk) {
            const float x = Xs[ty * 132 + kc * 16 + kk];
            #pragma unroll
            for (int j4 = 0; j4 < 4; ++j4) {
                const float4 a4 = *(const float4*)&Ck[kk * 132 + 4 * tx + 32 * j4];
                acc2[j4].x += x * a4.x; acc2[j4].y += x * a4.y;
                acc2[j4].z += x * a4.z; acc2[j4].w += x * a4.w;
            }
        }
    }
    float* dst = gtype ? Gout : Cout;
    #pragma unroll
    for (int j4 = 0; j4 < 4; ++j4)
        *(float4*)&dst[(size_t)b * DD + (i0 + ty) * D + 4 * tx + 32 * j4] = acc2[j4];
}

// ---------------------------------------------------------------------------
// zf: Zout = Z0 @ C (C includes identity). grid (32 row-slices, 8 b).
// ---------------------------------------------------------------------------
__global__ __launch_bounds__(256) void zf_kernel(
    const float* __restrict__ Z0, const float* __restrict__ C, float* __restrict__ out)
{
    const int s = blockIdx.x;   // 0..31
    const int b = blockIdx.y;
    const int t = threadIdx.x;
    const int ty = t >> 3, tx = t & 7;

    __shared__ float Zs[32 * 132];
    __shared__ float Ck[16 * 132];

    #pragma unroll
    for (int e = 0; e < 4; ++e) {
        const int idx4 = t + 256 * e;
        const int pos = idx4 << 2;
        *(float4*)&Zs[(pos >> 7) * 132 + (pos & 127)] =
            ((const float4*)Z0)[(size_t)(b * NP1 + s * 32) * 32 + idx4];
    }

    float4 acc[4] = {make_float4(0,0,0,0), make_float4(0,0,0,0),
                     make_float4(0,0,0,0), make_float4(0,0,0,0)};
    for (int kc = 0; kc < 8; ++kc) {
        __syncthreads();
        #pragma unroll
        for (int u = 0; u < 2; ++u) {
            const int idx4 = t + 256 * u;
            const int pos = idx4 << 2;
            *(float4*)&Ck[(pos >> 7) * 132 + (pos & 127)] =
                ((const float4*)C)[(size_t)b * 4096 + kc * 512 + idx4];
        }
        __syncthreads();
        #pragma unroll
        for (int kk = 0; kk < 16; ++kk) {
            const float x = Zs[ty * 132 + kc * 16 + kk];
            #pragma unroll
            for (int j4 = 0; j4 < 4; ++j4) {
                const float4 a4 = *(const float4*)&Ck[kk * 132 + 4 * tx + 32 * j4];
                acc[j4].x += x * a4.x; acc[j4].y += x * a4.y;
                acc[j4].z += x * a4.z; acc[j4].w += x * a4.w;
            }
        }
    }
    float* Orow = out + ((size_t)b * NP1 + s * 32 + ty) * D;
    #pragma unroll
    for (int j4 = 0; j4 < 4; ++j4)
        *(float4*)(Orow + 4 * tx + 32 * j4) = acc[j4];
}

// ---------------------------------------------------------------------------
extern "C" void kernel_launch(void* const* d_in, const int* in_sizes, int n_in,
                              void* d_out, int out_size, void* d_ws, size_t ws_size,
                              hipStream_t stream)
{
    const float* Z0 = (const float*)d_in[0];
    const float* ap = (const float*)d_in[1];
    float* out = (float*)d_out;
    float* ws  = (float*)d_ws;

    float* Gp = ws;                 // 524288
    float* S  = ws + 524288;        // 524288 (4 layers x 131072)
    float* GA = ws + 1048576;       // 131072
    float* GB = GA + 131072;
    float* CA = GB + 131072;
    float* CB = CA + 131072;
    const size_t LST = (size_t)H * 2 * DM * DM;   // param layer stride
    const int SST = 131072;                        // S layer stride

    hipLaunchKernelGGL(init_kernel, dim3(256), dim3(256), 0, stream, Z0, Gp, CA, S);
    // layer 0 (G from Gp reduce; C0 = I in CA)
    hipLaunchKernelGGL(sp_kernel,  dim3(4, H, B), dim3(256), 0, stream, ap,           Gp, S,          1);
    hipLaunchKernelGGL(upd_kernel, dim3(8, B),    dim3(256), 0, stream, S,            Gp, CA, GA, CB, 1, 1);
    // layer 1
    hipLaunchKernelGGL(sp_kernel,  dim3(4, H, B), dim3(256), 0, stream, ap + LST,     GA, S + SST,    0);
    hipLaunchKernelGGL(upd_kernel, dim3(8, B),    dim3(256), 0, stream, S + SST,      GA, CB, GB, CA, 0, 1);
    // layer 2
    hipLaunchKernelGGL(sp_kernel,  dim3(4, H, B), dim3(256), 0, stream, ap + 2 * LST, GB, S + 2 * SST, 0);
    hipLaunchKernelGGL(upd_kernel, dim3(8, B),    dim3(256), 0, stream, S + 2 * SST,  GB, CA, GA, CB, 0, 1);
    // layer 3 (no G update needed)
    hipLaunchKernelGGL(sp_kernel,  dim3(4, H, B), dim3(256), 0, stream, ap + 3 * LST, GA, S + 3 * SST, 0);
    hipLaunchKernelGGL(upd_kernel, dim3(8, B),    dim3(256), 0, stream, S + 3 * SST,  GA, CB, GB, CA, 0, 0);
    // final: Zout = Z0 @ C4 (in CA)
    hipLaunchKernelGGL(zf_kernel,  dim3(32, B),   dim3(256), 0, stream, Z0, CA, out);
}

// Round 7
// 307.732 us; speedup vs baseline: 2.9197x; 2.9197x over previous
//
#include <hip/hip_runtime.h>

// Problem constants
#define D    128      // d+1
#define DM   127      // d
#define NP1  1024     // N+1
#define B    8
#define H    8
#define NL   4
#define DD   16384    // 128*128
#define INVN (1.0f / 1023.0f)

// Workspace (float offsets) — exactly 6 MB (round-3 proven size)
// Gp [B][4][128][128]  : 524288   (Gram partials, 4 token-chunks of 256)
// S  [NL][B][128][128] : 524288   (head-reduced raw S sums, atomically built)
// GA/GB [B][128][128]  : 131072 each (G ping-pong)
// CA/CB [B][128][128]  : 131072 each (C ping-pong)

// ---------------------------------------------------------------------------
// init: C=I, S[0..3]=0, Gram partials Gp from Z0. 256 blocks.
// block gid -> (c:4 token-chunks of 256, q:8 col-slices of 16, b:8)
// ---------------------------------------------------------------------------
__global__ __launch_bounds__(256) void init_kernel(
    const float* __restrict__ Z0, float* __restrict__ Gp,
    float* __restrict__ Cid, float* __restrict__ Sz)
{
    const int gid = blockIdx.x;
    const int t = threadIdx.x;
    __shared__ float lds[64 * 128];   // 32 KB

    // C = I (131072 elems, 2 per thread)
    #pragma unroll
    for (int e = 0; e < 2; ++e) {
        const int idx = gid * 256 + t + 65536 * e;
        const int r = (idx >> 7) & 127, c = idx & 127;
        Cid[idx] = (r == c) ? 1.f : 0.f;
    }
    // S[0..3] = 0 (131072 float4, 2 per thread)
    #pragma unroll
    for (int e = 0; e < 2; ++e)
        ((float4*)Sz)[gid * 256 + t + 65536 * e] = make_float4(0.f, 0.f, 0.f, 0.f);

    // Gram partials
    const int c = gid & 3;
    const int q = (gid >> 2) & 7;
    const int b = gid >> 5;
    const int i0 = 4 * (t >> 3);          // rows i0..i0+4
    const int j0 = q * 16 + 2 * (t & 7);  // 2 cols

    float acc[4][2] = {};
    #pragma unroll
    for (int pass = 0; pass < 4; ++pass) {
        __syncthreads();
        const float4* src = (const float4*)(Z0 + ((size_t)b * NP1 + c * 256 + pass * 64) * D);
        #pragma unroll
        for (int i = 0; i < 8; ++i) {
            float4 v = src[t + 256 * i];
            // token 1023 (key-masked) = chunk 3, pass 3, last 8 rows
            if (c == 3 && pass == 3 && i == 7 && t >= 224) v = make_float4(0.f, 0.f, 0.f, 0.f);
            ((float4*)lds)[t + 256 * i] = v;
        }
        __syncthreads();
        #pragma unroll 4
        for (int k = 0; k < 64; ++k) {
            const float4 a = *(const float4*)&lds[k * 128 + i0];
            const float c0 = lds[k * 128 + j0];
            const float c1 = lds[k * 128 + j0 + 1];
            acc[0][0] += a.x * c0; acc[0][1] += a.x * c1;
            acc[1][0] += a.y * c0; acc[1][1] += a.y * c1;
            acc[2][0] += a.z * c0; acc[2][1] += a.z * c1;
            acc[3][0] += a.w * c0; acc[3][1] += a.w * c1;
        }
    }
    float* Gb = Gp + (size_t)(b * 4 + c) * DD;
    #pragma unroll
    for (int r = 0; r < 4; ++r)
        *(float2*)&Gb[(i0 + r) * D + j0] = make_float2(acc[r][0], acc[r][1]);
}

// ---------------------------------------------------------------------------
// sp: S_l[b] += Q̂_h G P̂_hᵀ (atomic over heads). grid (4 slices, 8 h, 8 b).
// Q̂/P̂ staged padded directly from raw params. gp_mode: G = sum of 4 Gp chunks.
// ---------------------------------------------------------------------------
__global__ __launch_bounds__(256) void sp_kernel(
    const float* __restrict__ apl, const float* __restrict__ Gsrc,
    float* __restrict__ Sl, int gp_mode)
{
    const int s = blockIdx.x;   // 0..3
    const int h = blockIdx.y;
    const int b = blockIdx.z;
    const int t = threadIdx.x;
    const int ty = t >> 3;      // 0..31 local row
    const int tx = t & 7;
    const int i0 = s * 32;

    __shared__ float Qs[32 * 132];
    __shared__ float Ck[16 * 132];
    __shared__ float Ts[32 * 132];

    // stage padded Q̂ rows [i0, i0+32)   (Q = params[:,1])
    const float* Qsrc = apl + (h * 2 + 1) * DM * DM;
    #pragma unroll
    for (int e = 0; e < 16; ++e) {
        const int idx = t + 256 * e;          // 0..4095
        const int rr = idx >> 7, c = idx & 127;
        const int r = i0 + rr;
        Qs[rr * 132 + c] = (r < DM && c < DM) ? Qsrc[r * DM + c] : 0.f;
    }

    // ---- phase 1: T = Q̂_slice @ G ----
    float4 acc[4] = {make_float4(0,0,0,0), make_float4(0,0,0,0),
                     make_float4(0,0,0,0), make_float4(0,0,0,0)};
    for (int kc = 0; kc < 8; ++kc) {
        __syncthreads();   // covers Qs on kc==0, Ck reuse after
        #pragma unroll
        for (int u = 0; u < 2; ++u) {
            const int idx4 = t + 256 * u;     // 0..511 (float4 within 16x128)
            float4 v;
            if (gp_mode) {
                v = make_float4(0.f, 0.f, 0.f, 0.f);
                #pragma unroll
                for (int cc = 0; cc < 4; ++cc) {
                    const float4 g = ((const float4*)Gsrc)[(size_t)(b * 4 + cc) * 4096 + kc * 512 + idx4];
                    v.x += g.x; v.y += g.y; v.z += g.z; v.w += g.w;
                }
            } else {
                v = ((const float4*)Gsrc)[(size_t)b * 4096 + kc * 512 + idx4];
            }
            const int pos = idx4 << 2;
            *(float4*)&Ck[(pos >> 7) * 132 + (pos & 127)] = v;
        }
        __syncthreads();
        #pragma unroll
        for (int kk = 0; kk < 16; ++kk) {
            const float tv = Qs[ty * 132 + kc * 16 + kk];
            #pragma unroll
            for (int j4 = 0; j4 < 4; ++j4) {
                const float4 g = *(const float4*)&Ck[kk * 132 + 4 * tx + 32 * j4];
                acc[j4].x += tv * g.x; acc[j4].y += tv * g.y;
                acc[j4].z += tv * g.z; acc[j4].w += tv * g.w;
            }
        }
    }
    #pragma unroll
    for (int j4 = 0; j4 < 4; ++j4)
        *(float4*)&Ts[ty * 132 + 4 * tx + 32 * j4] = acc[j4];

    // ---- phase 2: out = T @ P̂ᵀ, P̂ rows staged padded (P = params[:,0]) ----
    const float* Psrc = apl + (h * 2 + 0) * DM * DM;
    for (int jc = 0; jc < 8; ++jc) {
        __syncthreads();   // covers Ts writes on jc==0, Pc(Ck) reuse after
        #pragma unroll
        for (int e = 0; e < 8; ++e) {
            const int idx = t + 256 * e;      // 0..2047
            const int jj = idx >> 7, k = idx & 127;
            const int j = jc * 16 + jj;
            float v;
            if (j < DM && k < DM)        v = Psrc[j * DM + k];
            else if (j == DM && k == DM) v = 1.f;
            else                         v = 0.f;
            Ck[jj * 132 + k] = v;
        }
        __syncthreads();
        float x0 = 0.f, x1 = 0.f;
        #pragma unroll 8
        for (int k4 = 0; k4 < 32; ++k4) {
            const float4 tv = *(const float4*)&Ts[ty * 132 + 4 * k4];
            const float4 p0 = *(const float4*)&Ck[tx * 132 + 4 * k4];
            const float4 p1 = *(const float4*)&Ck[(tx + 8) * 132 + 4 * k4];
            x0 += tv.x * p0.x + tv.y * p0.y + tv.z * p0.z + tv.w * p0.w;
            x1 += tv.x * p1.x + tv.y * p1.y + tv.z * p1.z + tv.w * p1.w;
        }
        atomicAdd(&Sl[(size_t)b * DD + (i0 + ty) * D + jc * 16 + tx], x0);
        atomicAdd(&Sl[(size_t)b * DD + (i0 + ty) * D + jc * 16 + tx + 8], x1);
    }
}

// ---------------------------------------------------------------------------
// upd: A = I + S/N;  G-blocks (s<4): Gout = Aᵀ G A;  C-blocks (s>=4): Cout = Cin A.
// grid (8, 8). gp_mode: G streamed as 4-chunk Gp reduce. do_g=0 skips G-blocks.
// NOTE: identity insertion uses branchless per-component compares — dynamic
// indexing into a float4 ((&v.x)[k-col]) demotes the vector to scratch and
// caused 147 MB/dispatch of spill traffic in round 6.
// ---------------------------------------------------------------------------
__global__ __launch_bounds__(256) void upd_kernel(
    const float* __restrict__ Sl, const float* __restrict__ Gsrc,
    const float* __restrict__ Cin, float* __restrict__ Gout,
    float* __restrict__ Cout, int gp_mode, int do_g)
{
    const int s = blockIdx.x;   // 0..7
    const int b = blockIdx.y;
    const int t = threadIdx.x;
    const int ty = t >> 3, tx = t & 7;
    const bool gtype = (s < 4);
    const int i0 = (gtype ? s : s - 4) * 32;

    if (gtype && !do_g) return;

    __shared__ float Acs[128 * 36];
    __shared__ float Ck[16 * 132];
    __shared__ float Xs[32 * 132];

    if (gtype) {
        // Acs[k][ii] = A[k][i0+ii]
        #pragma unroll
        for (int e = 0; e < 16; ++e) {
            const int idx = t + 256 * e;       // 0..4095
            const int k = idx >> 5, ii = idx & 31;
            float v = INVN * Sl[(size_t)b * DD + k * D + i0 + ii];
            if (k == i0 + ii) v += 1.f;
            Acs[k * 36 + ii] = v;
        }
        __syncthreads();
        // phase A: X = A_colsliceᵀ @ G
        float4 acc[4] = {make_float4(0,0,0,0), make_float4(0,0,0,0),
                         make_float4(0,0,0,0), make_float4(0,0,0,0)};
        for (int kc = 0; kc < 8; ++kc) {
            if (kc) __syncthreads();
            #pragma unroll
            for (int u = 0; u < 2; ++u) {
                const int idx4 = t + 256 * u;
                float4 v;
                if (gp_mode) {
                    v = make_float4(0.f, 0.f, 0.f, 0.f);
                    #pragma unroll
                    for (int cc = 0; cc < 4; ++cc) {
                        const float4 g = ((const float4*)Gsrc)[(size_t)(b * 4 + cc) * 4096 + kc * 512 + idx4];
                        v.x += g.x; v.y += g.y; v.z += g.z; v.w += g.w;
                    }
                } else {
                    v = ((const float4*)Gsrc)[(size_t)b * 4096 + kc * 512 + idx4];
                }
                const int pos = idx4 << 2;
                *(float4*)&Ck[(pos >> 7) * 132 + (pos & 127)] = v;
            }
            __syncthreads();
            #pragma unroll
            for (int kk = 0; kk < 16; ++kk) {
                const float a = Acs[(kc * 16 + kk) * 36 + ty];
                #pragma unroll
                for (int j4 = 0; j4 < 4; ++j4) {
                    const float4 g = *(const float4*)&Ck[kk * 132 + 4 * tx + 32 * j4];
                    acc[j4].x += a * g.x; acc[j4].y += a * g.y;
                    acc[j4].z += a * g.z; acc[j4].w += a * g.w;
                }
            }
        }
        #pragma unroll
        for (int j4 = 0; j4 < 4; ++j4)
            *(float4*)&Xs[ty * 132 + 4 * tx + 32 * j4] = acc[j4];
    } else {
        // X = Cin rows [i0, i0+32)
        #pragma unroll
        for (int e = 0; e < 4; ++e) {
            const int idx4 = t + 256 * e;       // 0..1023 float4 of 32x128
            const int pos = idx4 << 2;
            *(float4*)&Xs[(pos >> 7) * 132 + (pos & 127)] =
                ((const float4*)Cin)[(size_t)b * 4096 + i0 * 32 + idx4];
        }
    }

    // ---- phase B: Out rows = X @ A ----
    float4 acc2[4] = {make_float4(0,0,0,0), make_float4(0,0,0,0),
                      make_float4(0,0,0,0), make_float4(0,0,0,0)};
    for (int kc = 0; kc < 8; ++kc) {
        __syncthreads();   // covers Xs writes on kc==0 and Ck reuse
        #pragma unroll
        for (int u = 0; u < 2; ++u) {
            const int idx4 = t + 256 * u;
            const int pos = idx4 << 2;
            const int kk = pos >> 7, col = pos & 127;
            const float4 sv = ((const float4*)Sl)[(size_t)b * 4096 + kc * 512 + idx4];
            float4 v = make_float4(sv.x * INVN, sv.y * INVN, sv.z * INVN, sv.w * INVN);
            const int k = kc * 16 + kk;
            // branchless identity insertion (NO dynamic vector indexing)
            v.x += (k == col)     ? 1.f : 0.f;
            v.y += (k == col + 1) ? 1.f : 0.f;
            v.z += (k == col + 2) ? 1.f : 0.f;
            v.w += (k == col + 3) ? 1.f : 0.f;
            *(float4*)&Ck[kk * 132 + col] = v;
        }
        __syncthreads();
        #pragma unroll
        for (int kk = 0; kk < 16; ++kk) {
            const float x = Xs[ty * 132 + kc * 16 + kk];
            #pragma unroll
            for (int j4 = 0; j4 < 4; ++j4) {
                const float4 a4 = *(const float4*)&Ck[kk * 132 + 4 * tx + 32 * j4];
                acc2[j4].x += x * a4.x; acc2[j4].y += x * a4.y;
                acc2[j4].z += x * a4.z; acc2[j4].w += x * a4.w;
            }
        }
    }
    float* dst = gtype ? Gout : Cout;
    #pragma unroll
    for (int j4 = 0; j4 < 4; ++j4)
        *(float4*)&dst[(size_t)b * DD + (i0 + ty) * D + 4 * tx + 32 * j4] = acc2[j4];
}

// ---------------------------------------------------------------------------
// zf: Zout = Z0 @ C (C includes identity). grid (32 row-slices, 8 b).
// ---------------------------------------------------------------------------
__global__ __launch_bounds__(256) void zf_kernel(
    const float* __restrict__ Z0, const float* __restrict__ C, float* __restrict__ out)
{
    const int s = blockIdx.x;   // 0..31
    const int b = blockIdx.y;
    const int t = threadIdx.x;
    const int ty = t >> 3, tx = t & 7;

    __shared__ float Zs[32 * 132];
    __shared__ float Ck[16 * 132];

    #pragma unroll
    for (int e = 0; e < 4; ++e) {
        const int idx4 = t + 256 * e;
        const int pos = idx4 << 2;
        *(float4*)&Zs[(pos >> 7) * 132 + (pos & 127)] =
            ((const float4*)Z0)[(size_t)(b * NP1 + s * 32) * 32 + idx4];
    }

    float4 acc[4] = {make_float4(0,0,0,0), make_float4(0,0,0,0),
                     make_float4(0,0,0,0), make_float4(0,0,0,0)};
    for (int kc = 0; kc < 8; ++kc) {
        __syncthreads();
        #pragma unroll
        for (int u = 0; u < 2; ++u) {
            const int idx4 = t + 256 * u;
            const int pos = idx4 << 2;
            *(float4*)&Ck[(pos >> 7) * 132 + (pos & 127)] =
                ((const float4*)C)[(size_t)b * 4096 + kc * 512 + idx4];
        }
        __syncthreads();
        #pragma unroll
        for (int kk = 0; kk < 16; ++kk) {
            const float x = Zs[ty * 132 + kc * 16 + kk];
            #pragma unroll
            for (int j4 = 0; j4 < 4; ++j4) {
                const float4 a4 = *(const float4*)&Ck[kk * 132 + 4 * tx + 32 * j4];
                acc[j4].x += x * a4.x; acc[j4].y += x * a4.y;
                acc[j4].z += x * a4.z; acc[j4].w += x * a4.w;
            }
        }
    }
    float* Orow = out + ((size_t)b * NP1 + s * 32 + ty) * D;
    #pragma unroll
    for (int j4 = 0; j4 < 4; ++j4)
        *(float4*)(Orow + 4 * tx + 32 * j4) = acc[j4];
}

// ---------------------------------------------------------------------------
extern "C" void kernel_launch(void* const* d_in, const int* in_sizes, int n_in,
                              void* d_out, int out_size, void* d_ws, size_t ws_size,
                              hipStream_t stream)
{
    const float* Z0 = (const float*)d_in[0];
    const float* ap = (const float*)d_in[1];
    float* out = (float*)d_out;
    float* ws  = (float*)d_ws;

    float* Gp = ws;                 // 524288
    float* S  = ws + 524288;        // 524288 (4 layers x 131072)
    float* GA = ws + 1048576;       // 131072
    float* GB = GA + 131072;
    float* CA = GB + 131072;
    float* CB = CA + 131072;
    const size_t LST = (size_t)H * 2 * DM * DM;   // param layer stride
    const int SST = 131072;                        // S layer stride

    hipLaunchKernelGGL(init_kernel, dim3(256), dim3(256), 0, stream, Z0, Gp, CA, S);
    // layer 0 (G from Gp reduce; C0 = I in CA)
    hipLaunchKernelGGL(sp_kernel,  dim3(4, H, B), dim3(256), 0, stream, ap,           Gp, S,          1);
    hipLaunchKernelGGL(upd_kernel, dim3(8, B),    dim3(256), 0, stream, S,            Gp, CA, GA, CB, 1, 1);
    // layer 1
    hipLaunchKernelGGL(sp_kernel,  dim3(4, H, B), dim3(256), 0, stream, ap + LST,     GA, S + SST,    0);
    hipLaunchKernelGGL(upd_kernel, dim3(8, B),    dim3(256), 0, stream, S + SST,      GA, CB, GB, CA, 0, 1);
    // layer 2
    hipLaunchKernelGGL(sp_kernel,  dim3(4, H, B), dim3(256), 0, stream, ap + 2 * LST, GB, S + 2 * SST, 0);
    hipLaunchKernelGGL(upd_kernel, dim3(8, B),    dim3(256), 0, stream, S + 2 * SST,  GB, CA, GA, CB, 0, 1);
    // layer 3 (no G update needed)
    hipLaunchKernelGGL(sp_kernel,  dim3(4, H, B), dim3(256), 0, stream, ap + 3 * LST, GA, S + 3 * SST, 0);
    hipLaunchKernelGGL(upd_kernel, dim3(8, B),    dim3(256), 0, stream, S + 3 * SST,  GA, CB, GB, CA, 0, 0);
    // final: Zout = Z0 @ C4 (in CA)
    hipLaunchKernelGGL(zf_kernel,  dim3(32, B),   dim3(256), 0, stream, Z0, CA, out);
}

// Round 8
// 284.008 us; speedup vs baseline: 3.1636x; 1.0835x over previous
//
#include <hip/hip_runtime.h>

// Problem constants
#define D    128      // d+1
#define DM   127      // d
#define NP1  1024     // N+1
#define B    8
#define H    8
#define NL   4
#define DD   16384    // 128*128
#define INVN (1.0f / 1023.0f)

// Workspace (float offsets) — exactly 6 MB (proven size)
// Gp [B][4][128][128]  : 524288   (Gram partials, 4 token-chunks of 256)
// S  [NL][B][128][128] : 524288   (head-reduced raw S sums, atomically built)
// GA/GB [B][128][128]  : 131072 each (G ping-pong)
// CA/CB [B][128][128]  : 131072 each (C ping-pong)

// ---------------------------------------------------------------------------
// init: C=I, S[0..3]=0, Gram partials Gp from Z0. 256 blocks.
// ---------------------------------------------------------------------------
__global__ __launch_bounds__(256) void init_kernel(
    const float* __restrict__ Z0, float* __restrict__ Gp,
    float* __restrict__ Cid, float* __restrict__ Sz)
{
    const int gid = blockIdx.x;
    const int t = threadIdx.x;
    __shared__ float lds[64 * 128];   // 32 KB

    #pragma unroll
    for (int e = 0; e < 2; ++e) {
        const int idx = gid * 256 + t + 65536 * e;
        const int r = (idx >> 7) & 127, c = idx & 127;
        Cid[idx] = (r == c) ? 1.f : 0.f;
    }
    #pragma unroll
    for (int e = 0; e < 2; ++e)
        ((float4*)Sz)[gid * 256 + t + 65536 * e] = make_float4(0.f, 0.f, 0.f, 0.f);

    const int c = gid & 3;
    const int q = (gid >> 2) & 7;
    const int b = gid >> 5;
    const int i0 = 4 * (t >> 3);
    const int j0 = q * 16 + 2 * (t & 7);

    float acc[4][2] = {};
    #pragma unroll
    for (int pass = 0; pass < 4; ++pass) {
        __syncthreads();
        const float4* src = (const float4*)(Z0 + ((size_t)b * NP1 + c * 256 + pass * 64) * D);
        #pragma unroll
        for (int i = 0; i < 8; ++i) {
            float4 v = src[t + 256 * i];
            if (c == 3 && pass == 3 && i == 7 && t >= 224) v = make_float4(0.f, 0.f, 0.f, 0.f);
            ((float4*)lds)[t + 256 * i] = v;
        }
        __syncthreads();
        #pragma unroll 4
        for (int k = 0; k < 64; ++k) {
            const float4 a = *(const float4*)&lds[k * 128 + i0];
            const float c0 = lds[k * 128 + j0];
            const float c1 = lds[k * 128 + j0 + 1];
            acc[0][0] += a.x * c0; acc[0][1] += a.x * c1;
            acc[1][0] += a.y * c0; acc[1][1] += a.y * c1;
            acc[2][0] += a.z * c0; acc[2][1] += a.z * c1;
            acc[3][0] += a.w * c0; acc[3][1] += a.w * c1;
        }
    }
    float* Gb = Gp + (size_t)(b * 4 + c) * DD;
    #pragma unroll
    for (int r = 0; r < 4; ++r)
        *(float2*)&Gb[(i0 + r) * D + j0] = make_float2(acc[r][0], acc[r][1]);
}

// ---------------------------------------------------------------------------
// sp v2: S_l[b] += Q̂_h G P̂_hᵀ. grid (4 slices, 8 h, 8 b).
// 4x4 register tiles, transposed LDS operands (b128 both sides),
// double-buffered chunk staging, single end-of-kernel atomic burst.
// ---------------------------------------------------------------------------
__global__ __launch_bounds__(256) void sp_kernel(
    const float* __restrict__ apl, const float* __restrict__ Gsrc,
    float* __restrict__ Sl, int gp_mode)
{
    const int s = blockIdx.x;   // 0..3
    const int h = blockIdx.y;
    const int b = blockIdx.z;
    const int t = threadIdx.x;
    const int tyi = t >> 5;     // 0..7  -> rows 4*tyi..4*tyi+3 (local)
    const int txj = t & 31;     // 0..31 -> cols 4*txj..4*txj+3
    const int i0 = s * 32;

    __shared__ float QsT[128 * 36];     // QsT[k][ii] = Q̂[i0+ii][k]
    __shared__ float TsT[128 * 36];     // TsT[k][ii] = T[i0+ii][k]
    __shared__ float Ck[2][16 * 128];   // double-buffered G / P̂ᵀ chunk

    // ---- stage QsT (transposed, padded; Q = params[:,1]) ----
    const float* Qsrc = apl + (h * 2 + 1) * DM * DM;
    {
        const int ii = t & 31;
        const int k0 = t >> 5;          // 0..7
        const int r = i0 + ii;
        #pragma unroll
        for (int e = 0; e < 16; ++e) {
            const int k = k0 + 8 * e;
            QsT[k * 36 + ii] = (r < DM && k < DM) ? Qsrc[r * DM + k] : 0.f;
        }
    }

    // ---- phase 1: T = Q̂_slice @ G (G = sum of Gp chunks if gp_mode) ----
    const float4* Gp4 = (const float4*)Gsrc;
    float4 pr0, pr1;
    // prefetch chunk 0
    {
        if (gp_mode) {
            pr0 = make_float4(0.f, 0.f, 0.f, 0.f); pr1 = pr0;
            #pragma unroll
            for (int cc = 0; cc < 4; ++cc) {
                const float4 g0 = Gp4[(size_t)(b * 4 + cc) * 4096 + t];
                const float4 g1 = Gp4[(size_t)(b * 4 + cc) * 4096 + 256 + t];
                pr0.x += g0.x; pr0.y += g0.y; pr0.z += g0.z; pr0.w += g0.w;
                pr1.x += g1.x; pr1.y += g1.y; pr1.z += g1.z; pr1.w += g1.w;
            }
        } else {
            pr0 = Gp4[(size_t)b * 4096 + t];
            pr1 = Gp4[(size_t)b * 4096 + 256 + t];
        }
    }

    float4 acc[4] = {make_float4(0,0,0,0), make_float4(0,0,0,0),
                     make_float4(0,0,0,0), make_float4(0,0,0,0)};
    for (int kc = 0; kc < 8; ++kc) {
        float* buf = Ck[kc & 1];
        ((float4*)buf)[t]       = pr0;
        ((float4*)buf)[256 + t] = pr1;
        __syncthreads();   // buf + (QsT on kc==0) visible
        if (kc < 7) {
            const int kn = kc + 1;
            if (gp_mode) {
                pr0 = make_float4(0.f, 0.f, 0.f, 0.f); pr1 = pr0;
                #pragma unroll
                for (int cc = 0; cc < 4; ++cc) {
                    const float4 g0 = Gp4[(size_t)(b * 4 + cc) * 4096 + kn * 512 + t];
                    const float4 g1 = Gp4[(size_t)(b * 4 + cc) * 4096 + kn * 512 + 256 + t];
                    pr0.x += g0.x; pr0.y += g0.y; pr0.z += g0.z; pr0.w += g0.w;
                    pr1.x += g1.x; pr1.y += g1.y; pr1.z += g1.z; pr1.w += g1.w;
                }
            } else {
                pr0 = Gp4[(size_t)b * 4096 + kn * 512 + t];
                pr1 = Gp4[(size_t)b * 4096 + kn * 512 + 256 + t];
            }
        }
        #pragma unroll
        for (int kk = 0; kk < 16; ++kk) {
            const float4 q4 = *(const float4*)&QsT[(kc * 16 + kk) * 36 + 4 * tyi];
            const float4 g4 = *(const float4*)&buf[kk * 128 + 4 * txj];
            acc[0].x += q4.x * g4.x; acc[0].y += q4.x * g4.y; acc[0].z += q4.x * g4.z; acc[0].w += q4.x * g4.w;
            acc[1].x += q4.y * g4.x; acc[1].y += q4.y * g4.y; acc[1].z += q4.y * g4.z; acc[1].w += q4.y * g4.w;
            acc[2].x += q4.z * g4.x; acc[2].y += q4.z * g4.y; acc[2].z += q4.z * g4.z; acc[2].w += q4.z * g4.w;
            acc[3].x += q4.w * g4.x; acc[3].y += q4.w * g4.y; acc[3].z += q4.w * g4.z; acc[3].w += q4.w * g4.w;
        }
        __syncthreads();   // all lanes done with buf before it's rewritten in 2 rounds
    }

    // ---- write T transposed to LDS ----
    // thread rows i_local = 4*tyi+a, cols k' = 4*txj+b -> TsT[k'][i_local]
    #pragma unroll
    for (int a = 0; a < 4; ++a) {
        TsT[(4 * txj + 0) * 36 + 4 * tyi + a] = (&acc[a].x)[0];
        TsT[(4 * txj + 1) * 36 + 4 * tyi + a] = (a == 0) ? acc[0].y : ((a == 1) ? acc[1].y : ((a == 2) ? acc[2].y : acc[3].y));
        TsT[(4 * txj + 2) * 36 + 4 * tyi + a] = (a == 0) ? acc[0].z : ((a == 1) ? acc[1].z : ((a == 2) ? acc[2].z : acc[3].z));
        TsT[(4 * txj + 3) * 36 + 4 * tyi + a] = (a == 0) ? acc[0].w : ((a == 1) ? acc[1].w : ((a == 2) ? acc[2].w : acc[3].w));
    }

    // ---- phase 2: S_slice = T @ P̂ᵀ ; Pt[k][j] = P̂[j][k] (P = params[:,0]) ----
    const float* Psrc = apl + (h * 2 + 0) * DM * DM;
    const int jP = t & 127;          // staging col
    const int kk0 = t >> 7;          // 0..1
    float pp[8];
    // prefetch chunk 0
    #pragma unroll
    for (int e = 0; e < 8; ++e) {
        const int kk = kk0 + 2 * e;
        const int k = kk;            // kc=0
        float v;
        if (jP < DM && k < DM)        v = Psrc[jP * DM + k];
        else if (jP == DM && k == DM) v = 1.f;
        else                          v = 0.f;
        pp[e] = v;
    }
    __syncthreads();   // TsT visible; phase-1 compute fully done

    float4 acc2[4] = {make_float4(0,0,0,0), make_float4(0,0,0,0),
                      make_float4(0,0,0,0), make_float4(0,0,0,0)};
    for (int kc = 0; kc < 8; ++kc) {
        float* buf = Ck[kc & 1];
        #pragma unroll
        for (int e = 0; e < 8; ++e)
            buf[(kk0 + 2 * e) * 128 + jP] = pp[e];
        __syncthreads();
        if (kc < 7) {
            #pragma unroll
            for (int e = 0; e < 8; ++e) {
                const int kk = kk0 + 2 * e;
                const int k = (kc + 1) * 16 + kk;
                float v;
                if (jP < DM && k < DM)        v = Psrc[jP * DM + k];
                else if (jP == DM && k == DM) v = 1.f;
                else                          v = 0.f;
                pp[e] = v;
            }
        }
        #pragma unroll
        for (int kk = 0; kk < 16; ++kk) {
            const float4 t4 = *(const float4*)&TsT[(kc * 16 + kk) * 36 + 4 * tyi];
            const float4 p4 = *(const float4*)&buf[kk * 128 + 4 * txj];
            acc2[0].x += t4.x * p4.x; acc2[0].y += t4.x * p4.y; acc2[0].z += t4.x * p4.z; acc2[0].w += t4.x * p4.w;
            acc2[1].x += t4.y * p4.x; acc2[1].y += t4.y * p4.y; acc2[1].z += t4.y * p4.z; acc2[1].w += t4.y * p4.w;
            acc2[2].x += t4.z * p4.x; acc2[2].y += t4.z * p4.y; acc2[2].z += t4.z * p4.z; acc2[2].w += t4.z * p4.w;
            acc2[3].x += t4.w * p4.x; acc2[3].y += t4.w * p4.y; acc2[3].z += t4.w * p4.z; acc2[3].w += t4.w * p4.w;
        }
        __syncthreads();
    }

    // ---- single atomic burst (no dynamic vector indexing) ----
    float* Sb = Sl + (size_t)b * DD;
    #pragma unroll
    for (int a = 0; a < 4; ++a) {
        float* row = Sb + (i0 + 4 * tyi + a) * D + 4 * txj;
        atomicAdd(row + 0, acc2[a].x);
        atomicAdd(row + 1, acc2[a].y);
        atomicAdd(row + 2, acc2[a].z);
        atomicAdd(row + 3, acc2[a].w);
    }
}

// ---------------------------------------------------------------------------
// upd: A = I + S/N;  G-blocks (s<4): Gout = Aᵀ G A;  C-blocks (s>=4): Cout = Cin A.
// grid (8, 8). Branchless identity insertion (round-6 spill lesson).
// ---------------------------------------------------------------------------
__global__ __launch_bounds__(256) void upd_kernel(
    const float* __restrict__ Sl, const float* __restrict__ Gsrc,
    const float* __restrict__ Cin, float* __restrict__ Gout,
    float* __restrict__ Cout, int gp_mode, int do_g)
{
    const int s = blockIdx.x;
    const int b = blockIdx.y;
    const int t = threadIdx.x;
    const int ty = t >> 3, tx = t & 7;
    const bool gtype = (s < 4);
    const int i0 = (gtype ? s : s - 4) * 32;

    if (gtype && !do_g) return;

    __shared__ float Acs[128 * 36];
    __shared__ float Ck[16 * 132];
    __shared__ float Xs[32 * 132];

    if (gtype) {
        #pragma unroll
        for (int e = 0; e < 16; ++e) {
            const int idx = t + 256 * e;
            const int k = idx >> 5, ii = idx & 31;
            float v = INVN * Sl[(size_t)b * DD + k * D + i0 + ii];
            if (k == i0 + ii) v += 1.f;
            Acs[k * 36 + ii] = v;
        }
        __syncthreads();
        float4 acc[4] = {make_float4(0,0,0,0), make_float4(0,0,0,0),
                         make_float4(0,0,0,0), make_float4(0,0,0,0)};
        for (int kc = 0; kc < 8; ++kc) {
            if (kc) __syncthreads();
            #pragma unroll
            for (int u = 0; u < 2; ++u) {
                const int idx4 = t + 256 * u;
                float4 v;
                if (gp_mode) {
                    v = make_float4(0.f, 0.f, 0.f, 0.f);
                    #pragma unroll
                    for (int cc = 0; cc < 4; ++cc) {
                        const float4 g = ((const float4*)Gsrc)[(size_t)(b * 4 + cc) * 4096 + kc * 512 + idx4];
                        v.x += g.x; v.y += g.y; v.z += g.z; v.w += g.w;
                    }
                } else {
                    v = ((const float4*)Gsrc)[(size_t)b * 4096 + kc * 512 + idx4];
                }
                const int pos = idx4 << 2;
                *(float4*)&Ck[(pos >> 7) * 132 + (pos & 127)] = v;
            }
            __syncthreads();
            #pragma unroll
            for (int kk = 0; kk < 16; ++kk) {
                const float a = Acs[(kc * 16 + kk) * 36 + ty];
                #pragma unroll
                for (int j4 = 0; j4 < 4; ++j4) {
                    const float4 g = *(const float4*)&Ck[kk * 132 + 4 * tx + 32 * j4];
                    acc[j4].x += a * g.x; acc[j4].y += a * g.y;
                    acc[j4].z += a * g.z; acc[j4].w += a * g.w;
                }
            }
        }
        #pragma unroll
        for (int j4 = 0; j4 < 4; ++j4)
            *(float4*)&Xs[ty * 132 + 4 * tx + 32 * j4] = acc[j4];
    } else {
        #pragma unroll
        for (int e = 0; e < 4; ++e) {
            const int idx4 = t + 256 * e;
            const int pos = idx4 << 2;
            *(float4*)&Xs[(pos >> 7) * 132 + (pos & 127)] =
                ((const float4*)Cin)[(size_t)b * 4096 + i0 * 32 + idx4];
        }
    }

    float4 acc2[4] = {make_float4(0,0,0,0), make_float4(0,0,0,0),
                      make_float4(0,0,0,0), make_float4(0,0,0,0)};
    for (int kc = 0; kc < 8; ++kc) {
        __syncthreads();
        #pragma unroll
        for (int u = 0; u < 2; ++u) {
            const int idx4 = t + 256 * u;
            const int pos = idx4 << 2;
            const int kk = pos >> 7, col = pos & 127;
            const float4 sv = ((const float4*)Sl)[(size_t)b * 4096 + kc * 512 + idx4];
            float4 v = make_float4(sv.x * INVN, sv.y * INVN, sv.z * INVN, sv.w * INVN);
            const int k = kc * 16 + kk;
            v.x += (k == col)     ? 1.f : 0.f;
            v.y += (k == col + 1) ? 1.f : 0.f;
            v.z += (k == col + 2) ? 1.f : 0.f;
            v.w += (k == col + 3) ? 1.f : 0.f;
            *(float4*)&Ck[kk * 132 + col] = v;
        }
        __syncthreads();
        #pragma unroll
        for (int kk = 0; kk < 16; ++kk) {
            const float x = Xs[ty * 132 + kc * 16 + kk];
            #pragma unroll
            for (int j4 = 0; j4 < 4; ++j4) {
                const float4 a4 = *(const float4*)&Ck[kk * 132 + 4 * tx + 32 * j4];
                acc2[j4].x += x * a4.x; acc2[j4].y += x * a4.y;
                acc2[j4].z += x * a4.z; acc2[j4].w += x * a4.w;
            }
        }
    }
    float* dst = gtype ? Gout : Cout;
    #pragma unroll
    for (int j4 = 0; j4 < 4; ++j4)
        *(float4*)&dst[(size_t)b * DD + (i0 + ty) * D + 4 * tx + 32 * j4] = acc2[j4];
}

// ---------------------------------------------------------------------------
// zf: Zout = Z0 @ C. grid (32 row-slices, 8 b).
// ---------------------------------------------------------------------------
__global__ __launch_bounds__(256) void zf_kernel(
    const float* __restrict__ Z0, const float* __restrict__ C, float* __restrict__ out)
{
    const int s = blockIdx.x;
    const int b = blockIdx.y;
    const int t = threadIdx.x;
    const int ty = t >> 3, tx = t & 7;

    __shared__ float Zs[32 * 132];
    __shared__ float Ck[16 * 132];

    #pragma unroll
    for (int e = 0; e < 4; ++e) {
        const int idx4 = t + 256 * e;
        const int pos = idx4 << 2;
        *(float4*)&Zs[(pos >> 7) * 132 + (pos & 127)] =
            ((const float4*)Z0)[(size_t)(b * NP1 + s * 32) * 32 + idx4];
    }

    float4 acc[4] = {make_float4(0,0,0,0), make_float4(0,0,0,0),
                     make_float4(0,0,0,0), make_float4(0,0,0,0)};
    for (int kc = 0; kc < 8; ++kc) {
        __syncthreads();
        #pragma unroll
        for (int u = 0; u < 2; ++u) {
            const int idx4 = t + 256 * u;
            const int pos = idx4 << 2;
            *(float4*)&Ck[(pos >> 7) * 132 + (pos & 127)] =
                ((const float4*)C)[(size_t)b * 4096 + kc * 512 + idx4];
        }
        __syncthreads();
        #pragma unroll
        for (int kk = 0; kk < 16; ++kk) {
            const float x = Zs[ty * 132 + kc * 16 + kk];
            #pragma unroll
            for (int j4 = 0; j4 < 4; ++j4) {
                const float4 a4 = *(const float4*)&Ck[kk * 132 + 4 * tx + 32 * j4];
                acc[j4].x += x * a4.x; acc[j4].y += x * a4.y;
                acc[j4].z += x * a4.z; acc[j4].w += x * a4.w;
            }
        }
    }
    float* Orow = out + ((size_t)b * NP1 + s * 32 + ty) * D;
    #pragma unroll
    for (int j4 = 0; j4 < 4; ++j4)
        *(float4*)(Orow + 4 * tx + 32 * j4) = acc[j4];
}

// ---------------------------------------------------------------------------
extern "C" void kernel_launch(void* const* d_in, const int* in_sizes, int n_in,
                              void* d_out, int out_size, void* d_ws, size_t ws_size,
                              hipStream_t stream)
{
    const float* Z0 = (const float*)d_in[0];
    const float* ap = (const float*)d_in[1];
    float* out = (float*)d_out;
    float* ws  = (float*)d_ws;

    float* Gp = ws;                 // 524288
    float* S  = ws + 524288;        // 524288 (4 layers x 131072)
    float* GA = ws + 1048576;       // 131072
    float* GB = GA + 131072;
    float* CA = GB + 131072;
    float* CB = CA + 131072;
    const size_t LST = (size_t)H * 2 * DM * DM;
    const int SST = 131072;

    hipLaunchKernelGGL(init_kernel, dim3(256), dim3(256), 0, stream, Z0, Gp, CA, S);
    hipLaunchKernelGGL(sp_kernel,  dim3(4, H, B), dim3(256), 0, stream, ap,           Gp, S,          1);
    hipLaunchKernelGGL(upd_kernel, dim3(8, B),    dim3(256), 0, stream, S,            Gp, CA, GA, CB, 1, 1);
    hipLaunchKernelGGL(sp_kernel,  dim3(4, H, B), dim3(256), 0, stream, ap + LST,     GA, S + SST,    0);
    hipLaunchKernelGGL(upd_kernel, dim3(8, B),    dim3(256), 0, stream, S + SST,      GA, CB, GB, CA, 0, 1);
    hipLaunchKernelGGL(sp_kernel,  dim3(4, H, B), dim3(256), 0, stream, ap + 2 * LST, GB, S + 2 * SST, 0);
    hipLaunchKernelGGL(upd_kernel, dim3(8, B),    dim3(256), 0, stream, S + 2 * SST,  GB, CA, GA, CB, 0, 1);
    hipLaunchKernelGGL(sp_kernel,  dim3(4, H, B), dim3(256), 0, stream, ap + 3 * LST, GA, S + 3 * SST, 0);
    hipLaunchKernelGGL(upd_kernel, dim3(8, B),    dim3(256), 0, stream, S + 3 * SST,  GA, CB, GB, CA, 0, 0);
    hipLaunchKernelGGL(zf_kernel,  dim3(32, B),   dim3(256), 0, stream, Z0, CA, out);
}